// Round 11
// baseline (128.781 us; speedup 1.0000x reference)
//
#include <hip/hip_runtime.h>
#include <hip/hip_fp16.h>
#include <cstddef>

#define G_N   10000
#define L_N   1000
#define NSTA  400
#define NSRC  2000
#define KK    15
#define CAP   512
#define NBLK  1250        // pack blocks; 8 rows each (1250*8 = 10000)

__device__ __forceinline__ float tr1k(float x) {
    // matches reference: _ftrns(x)/1000.0 = (x*1000.0f)/1000.0f, exact f32 div
    return (x * 1000.0f) / 1000.0f;
}

__device__ __forceinline__ float softplus(float x) {
    return fmaxf(x, 0.0f) + log1pf(expf(-fabsf(x)));
}

__device__ __forceinline__ float softplus_fast(float x) {
    return fmaxf(x, 0.0f) + __logf(1.0f + __expf(-fabsf(x)));
}

__device__ __forceinline__ bool lexless(float v1, int i1, float v2, int i2) {
    return (v1 < v2) || (v1 == v2 && i1 < i2);
}

// ---------------------------------------------------------------------------
// Kernel 1: sta_ind argmin (one wave per station) + tr1k precompute tables
// (tg = tr1k(x_grid), ts = tr1k(src)) + zero used[].
// ---------------------------------------------------------------------------
__global__ void sta_prep_kernel(const float* __restrict__ sta,
                                const float* __restrict__ locs_ref,
                                const float* __restrict__ x_grid,
                                const float* __restrict__ src,
                                int* __restrict__ sta_ind,
                                float* __restrict__ tg,
                                float* __restrict__ ts,
                                int* __restrict__ used) {
#pragma clang fp contract(off)
    const int i    = blockIdx.x;
    const int lane = threadIdx.x;

    const int z = i * 64 + lane;
    for (int p = z; p < 3 * (G_N + NSRC); p += 400 * 64) {
        if (p < 3 * G_N) tg[p] = tr1k(x_grid[p]);
        else             ts[p - 3 * G_N] = tr1k(src[p - 3 * G_N]);
    }
    if (used && z < G_N) used[z] = 0;   // 25600 threads >= G_N

    const float sx = tr1k(sta[i * 3 + 0]);
    const float sy = tr1k(sta[i * 3 + 1]);
    const float sz = tr1k(sta[i * 3 + 2]);
    float best = INFINITY;
    int   bidx = 0x7fffffff;
    for (int j = lane; j < L_N; j += 64) {
        float dx = sx - tr1k(locs_ref[j * 3 + 0]);
        float dy = sy - tr1k(locs_ref[j * 3 + 1]);
        float dz = sz - tr1k(locs_ref[j * 3 + 2]);
        float d  = (dx * dx + dy * dy) + dz * dz;
        if (lexless(d, j, best, bidx)) { best = d; bidx = j; }
    }
    for (int off = 1; off < 64; off <<= 1) {
        float ov = __shfl_xor(best, off);
        int   oi = __shfl_xor(bidx, off);
        if (lexless(ov, oi, best, bidx)) { best = ov; bidx = oi; }
    }
    if (lane == 0) sta_ind[i] = bidx;
}

// ---------------------------------------------------------------------------
// Kernel 2 (v5): exact threshold select; no divisions, no histogram,
// ~5 KB LDS. Unchanged this round.
// ---------------------------------------------------------------------------
__global__ __launch_bounds__(256, 8) void topk_only_kernel(
    const float* __restrict__ tg, const float* __restrict__ ts,
    int* __restrict__ idx_out, int* __restrict__ used)
{
#pragma clang fp contract(off)
    const int s    = blockIdx.x;
    const int tid  = threadIdx.x;
    const int lane = tid & 63;
    const int wv   = tid >> 6;

    __shared__ float s_min[256];
    __shared__ int   s_cand[CAP];
    __shared__ float s_cd[CAP];
    __shared__ float s_T;
    __shared__ int   s_cnt;
    __shared__ float s_mv[4];
    __shared__ int   s_mi[4];
    __shared__ int   s_ch[KK];

    if (tid == 0) s_cnt = 0;

    const float sx = ts[s * 3 + 0];
    const float sy = ts[s * 3 + 1];
    const float sz = ts[s * 3 + 2];

    // pass 1: per-thread min
    float mymin = INFINITY;
    for (int g = tid; g < G_N; g += 256) {
        float dx = sx - tg[g * 3 + 0];
        float dy = sy - tg[g * 3 + 1];
        float dz = sz - tg[g * 3 + 2];
        float d  = (dx * dx + dy * dy) + dz * dz;
        mymin = fminf(mymin, d);
    }
    s_min[tid] = mymin;
    __syncthreads();

    // wave 0: T = 15th smallest of 256 minima
    if (wv == 0) {
        float m0 = s_min[lane];
        float m1 = s_min[lane + 64];
        float m2 = s_min[lane + 128];
        float m3 = s_min[lane + 192];
        float T = INFINITY;
        for (int r = 0; r < KK; ++r) {
            float lv = m0; int ls = 0;
            if (m1 < lv) { lv = m1; ls = 1; }
            if (m2 < lv) { lv = m2; ls = 2; }
            if (m3 < lv) { lv = m3; ls = 3; }
            float v = lv; int wl = lane;
            for (int off = 1; off < 64; off <<= 1) {
                float ov = __shfl_xor(v, off);
                int   ol = __shfl_xor(wl, off);
                if (ov < v || (ov == v && ol < wl)) { v = ov; wl = ol; }
            }
            T = v;
            if (wl == lane) {
                if (ls == 0) m0 = INFINITY;
                else if (ls == 1) m1 = INFINITY;
                else if (ls == 2) m2 = INFINITY;
                else m3 = INFINITY;
            }
        }
        if (lane == 0) s_T = T;
    }
    __syncthreads();
    const float T = s_T;

    // pass 2: recompute, append survivors
    for (int g = tid; g < G_N; g += 256) {
        float dx = sx - tg[g * 3 + 0];
        float dy = sy - tg[g * 3 + 1];
        float dz = sz - tg[g * 3 + 2];
        float d  = (dx * dx + dy * dy) + dz * dz;
        if (d <= T) {
            int p = atomicAdd(&s_cnt, 1);
            if (p < CAP) { s_cand[p] = g; s_cd[p] = d; }
        }
    }
    __syncthreads();
    const int n = s_cnt;

    if (n <= CAP) {
        if (wv == 0) {
            float vals[KK];
            int   ids[KK];
#pragma unroll
            for (int j = 0; j < KK; ++j) { vals[j] = INFINITY; ids[j] = 0x7fffffff; }
            for (int c = lane; c < n; c += 64) {
                int   g = s_cand[c];
                float d = s_cd[c];
                if (lexless(d, g, vals[KK - 1], ids[KK - 1])) {
                    float cv = d; int ci = g;
#pragma unroll
                    for (int j = 0; j < KK; ++j) {
                        bool sw = lexless(cv, ci, vals[j], ids[j]);
                        float tv = sw ? vals[j] : cv;
                        int   ti = sw ? ids[j]  : ci;
                        vals[j]  = sw ? cv : vals[j];
                        ids[j]   = sw ? ci : ids[j];
                        cv = tv; ci = ti;
                    }
                }
            }
            for (int r = 0; r < KK; ++r) {
                float v  = vals[0];
                int   id = ids[0];
                int   who = lane;
                for (int off = 1; off < 64; off <<= 1) {
                    float ov = __shfl_xor(v, off);
                    int   oi = __shfl_xor(id, off);
                    int   ow = __shfl_xor(who, off);
                    if (lexless(ov, oi, v, id)) { v = ov; id = oi; who = ow; }
                }
                if (lane == 0) {
                    idx_out[s * KK + r] = id;
                    if (used) used[id] = 1;   // benign race; all writers store 1
                }
                if (who == lane) {
#pragma unroll
                    for (int j = 0; j < KK - 1; ++j) { vals[j] = vals[j + 1]; ids[j] = ids[j + 1]; }
                    vals[KK - 1] = INFINITY;
                    ids[KK - 1]  = 0x7fffffff;
                }
            }
        }
    } else {
        // degenerate-ties fallback: exact 15 rounds of block argmin
        for (int r = 0; r < KK; ++r) {
            float v  = INFINITY;
            int   id = 0x7fffffff;
            for (int g = tid; g < G_N; g += 256) {
                bool skip = false;
                for (int j = 0; j < r; ++j) skip = skip || (s_ch[j] == g);
                if (skip) continue;
                float dx = sx - tg[g * 3 + 0];
                float dy = sy - tg[g * 3 + 1];
                float dz = sz - tg[g * 3 + 2];
                float d  = (dx * dx + dy * dy) + dz * dz;
                if (lexless(d, g, v, id)) { v = d; id = g; }
            }
            for (int off = 1; off < 64; off <<= 1) {
                float ov = __shfl_xor(v, off);
                int   oi = __shfl_xor(id, off);
                if (lexless(ov, oi, v, id)) { v = ov; id = oi; }
            }
            if (lane == 0) { s_mv[wv] = v; s_mi[wv] = id; }
            __syncthreads();
            if (tid == 0) {
                float bv = s_mv[0]; int bi = s_mi[0];
                for (int w = 1; w < 4; ++w)
                    if (lexless(s_mv[w], s_mi[w], bv, bi)) { bv = s_mv[w]; bi = s_mi[w]; }
                s_ch[r] = bi;
                idx_out[s * KK + r] = bi;
                if (used) used[bi] = 1;
            }
            __syncthreads();
        }
    }
}

// ---------------------------------------------------------------------------
// Kernel 3: pack (fp16), software-pipelined (T3/T4 pattern).
// 1250 persistent blocks x 8 rows. Double-buffered 2x20KB LDS. Per row:
// issue next row's 5 global_load_lds per wave, counted s_waitcnt vmcnt(5)
// (waits only the CURRENT row; next row's DMA stays in flight), raw
// s_barrier, gather+convert+store, trailing s_barrier (buffer reuse safety).
// Loads never fully drain inside the loop -> memory pipe stays busy under
// the gather phase. Station indices hoisted out of the row loop.
// ---------------------------------------------------------------------------
__global__ __launch_bounds__(256) void pack_kernel(
    const float* __restrict__ coefs, const float* __restrict__ coefs_ker,
    const int* __restrict__ sta_ind, const int* __restrict__ phase,
    const int* __restrict__ used,
    uint2* __restrict__ pk)
{
    // [buf][0,3000) ker row, [buf][3000,5000) coef row, [buf][5000,5120) pad
    __shared__ __align__(16) float s_buf[2][5120];   // 40960 B -> 4 blocks/CU
    __shared__ int s_list[8];
    __shared__ int s_n;

    const int tid  = threadIdx.x;
    const int lane = tid & 63;
    const int wv   = tid >> 6;

    if (tid == 0) {
        int n = 0;
        for (int r = blockIdx.x; r < G_N; r += NBLK)
            if (used[r]) s_list[n++] = r;
        s_n = n;
    }
    __syncthreads();                 // full drain; clean vmcnt state
    const int n = s_n;
    if (n == 0) return;

    // station gather indices: loaded once, reused for all rows (4 VMEM loads)
    const int i1  = tid + 256;
    const int st0 = sta_ind[tid];                       // tid < 256 <= NSTA
    const int ph0 = phase[tid];
    const int st1 = (i1 < NSTA) ? sta_ind[i1] : 0;
    const int ph1 = (i1 < NSTA) ? phase[i1] : 0;

    auto stage = [&](int buf, int row) {
        const float4* kr4 = (const float4*)(coefs_ker + (size_t)row * (L_N * 3)); // 750 slots
        const float4* cr4 = (const float4*)(coefs     + (size_t)row * (L_N * 2)); // 500 slots
#pragma unroll
        for (int r = 0; r < 5; ++r) {
            const int chunk = wv * 5 + r;          // 0..19, wave-uniform
            const int slot  = chunk * 64 + lane;   // 0..1279 per-lane
            const float4* gp = (slot < 750) ? (kr4 + slot)
                             : (slot < 1250) ? (cr4 + (slot - 750))
                             : (cr4 + 499);        // clamped tail -> LDS pad
            __builtin_amdgcn_global_load_lds(
                (const __attribute__((address_space(1))) void*)gp,
                (__attribute__((address_space(3))) void*)(&s_buf[buf][0] + (size_t)chunk * 256),
                16, 0, 0);
        }
    };

    stage(0, s_list[0]);
    for (int r = 0; r < n; ++r) {
        const int cur = r & 1;
        if (r + 1 < n) {
            stage(cur ^ 1, s_list[r + 1]);         // prefetch next row
            asm volatile("s_waitcnt vmcnt(5)" ::: "memory");   // current row done
        } else {
            asm volatile("s_waitcnt vmcnt(0)" ::: "memory");
        }
        __builtin_amdgcn_s_barrier();              // all waves: row r in LDS
        __builtin_amdgcn_sched_barrier(0);         // rule #18: pin reads after wait

        const float* s_ker = &s_buf[cur][0];
        const float* s_c   = &s_buf[cur][3000];
        const int g = s_list[r];

        {
            float rk0 = 1.0f / softplus_fast(s_ker[st0 * 3 + 0]);
            float rk1 = 1.0f / softplus_fast(s_ker[st0 * 3 + 1]);
            float rk2 = 1.0f / softplus_fast(s_ker[st0 * 3 + 2]);
            float c   = (ph0 == 0) ? s_c[st0 * 2 + 0] : s_c[st0 * 2 + 1];
            __half2 a = __floats2half2_rn(rk0, rk1);
            __half2 b = __floats2half2_rn(rk2, c);
            uint2 u;
            u.x = *reinterpret_cast<unsigned int*>(&a);
            u.y = *reinterpret_cast<unsigned int*>(&b);
            pk[(size_t)g * NSTA + tid] = u;
        }
        if (i1 < NSTA) {
            float rk0 = 1.0f / softplus_fast(s_ker[st1 * 3 + 0]);
            float rk1 = 1.0f / softplus_fast(s_ker[st1 * 3 + 1]);
            float rk2 = 1.0f / softplus_fast(s_ker[st1 * 3 + 2]);
            float c   = (ph1 == 0) ? s_c[st1 * 2 + 0] : s_c[st1 * 2 + 1];
            __half2 a = __floats2half2_rn(rk0, rk1);
            __half2 b = __floats2half2_rn(rk2, c);
            uint2 u;
            u.x = *reinterpret_cast<unsigned int*>(&a);
            u.y = *reinterpret_cast<unsigned int*>(&b);
            pk[(size_t)g * NSTA + i1] = u;
        }
        __builtin_amdgcn_s_barrier();              // all waves done reading buf[cur]
    }
}

// ---------------------------------------------------------------------------
// Kernel 4: main fused computation, fast path (fp16 packed table).
// ---------------------------------------------------------------------------
__global__ __launch_bounds__(256, 8) void magnitude_fast_kernel(
    const float* __restrict__ sta, const float* __restrict__ src,
    const float* __restrict__ mag, const int* __restrict__ phase,
    const float* __restrict__ x_grid,
    const float* __restrict__ mag_coef, const float* __restrict__ epi_coef,
    const float* __restrict__ dep_coef,
    const uint2* __restrict__ pk, const int* __restrict__ idx,
    float* __restrict__ out)
{
    const int s   = blockIdx.x;
    const int tid = threadIdx.x;

    __shared__ float s_diff[KK][3];
    __shared__ int   s_g[KK];

    if (tid < KK) {
        int g = idx[s * KK + tid];
        s_g[tid] = g;
        s_diff[tid][0] = tr1k(x_grid[g * 3 + 0]) - tr1k(src[s * 3 + 0]);
        s_diff[tid][1] = tr1k(x_grid[g * 3 + 1]) - tr1k(src[s * 3 + 1]);
        s_diff[tid][2] = tr1k(x_grid[g * 3 + 2]) - tr1k(src[s * 3 + 2]);
    }
    __syncthreads();

    const float mag_s = mag[s];
    const float srcx = src[s * 3 + 0];
    const float srcy = src[s * 3 + 1];
    const float srcz = src[s * 3 + 2];
    const float sp_mc0 = softplus(mag_coef[0]), sp_mc1 = softplus(mag_coef[1]);
    const float sp_ec0 = softplus(epi_coef[0]), sp_ec1 = softplus(epi_coef[1]);
    const float dc0 = dep_coef[0], dc1 = dep_coef[1];

    for (int i = tid; i < NSTA; i += 256) {
        float wsum = 0.0f, a = 0.0f;
#pragma unroll
        for (int k = 0; k < KK; ++k) {
            uint2 u = pk[(size_t)s_g[k] * NSTA + i];
            __half2 h01 = *reinterpret_cast<const __half2*>(&u.x);
            __half2 h23 = *reinterpret_cast<const __half2*>(&u.y);
            float2 f01 = __half22float2(h01);
            float2 f23 = __half22float2(h23);
            float t0 = s_diff[k][0] * f01.x;
            float t1 = s_diff[k][1] * f01.y;
            float t2 = s_diff[k][2] * f23.x;
            float e  = __expf(-0.5f * ((t0 * t0 + t1 * t1) + t2 * t2));
            wsum += e;
            a    += e * f23.y;
        }
        if (wsum == 0.0f) wsum = 1.0f;

        const int ph = phase[i];
        float bias = a / wsum;

        float dx = srcx * 1000.0f - sta[i * 3 + 0] * 1000.0f;
        float dy = srcy * 1000.0f - sta[i * 3 + 1] * 1000.0f;
        float lz = __log10f(__fsqrt_rn(dx * dx + dy * dy) + 1.0f);
        float ld = __log10f(fabsf(srcz - sta[i * 3 + 2]) + 1.0f);

        float mc = (ph == 0) ? sp_mc0 : sp_mc1;
        float ec = (ph == 0) ? sp_ec0 : sp_ec1;
        float dc = (ph == 0) ? dc0 : dc1;

        out[(size_t)s * NSTA + i] = mag_s * mc - ec * lz + dc * ld + bias;
    }
}

// ---------------------------------------------------------------------------
// Fallback main kernel (direct gather) if ws can't hold the packed table.
// ---------------------------------------------------------------------------
__global__ __launch_bounds__(256) void magnitude_kernel(
    const float* __restrict__ sta, const float* __restrict__ src,
    const float* __restrict__ mag, const int* __restrict__ phase,
    const float* __restrict__ x_grid,
    const float* __restrict__ mag_coef, const float* __restrict__ epi_coef,
    const float* __restrict__ dep_coef,
    const float* __restrict__ coefs, const float* __restrict__ coefs_ker,
    const int* __restrict__ sta_ind, const int* __restrict__ idx,
    float* __restrict__ out)
{
    const int s   = blockIdx.x;
    const int tid = threadIdx.x;

    __shared__ float s_diff[KK][3];
    __shared__ int   s_g[KK];
    __shared__ int   s_sta[NSTA];

    if (tid < KK) {
        int g = idx[s * KK + tid];
        s_g[tid] = g;
        s_diff[tid][0] = tr1k(x_grid[g * 3 + 0]) - tr1k(src[s * 3 + 0]);
        s_diff[tid][1] = tr1k(x_grid[g * 3 + 1]) - tr1k(src[s * 3 + 1]);
        s_diff[tid][2] = tr1k(x_grid[g * 3 + 2]) - tr1k(src[s * 3 + 2]);
    }
    for (int i = tid; i < NSTA; i += 256) s_sta[i] = sta_ind[i];
    __syncthreads();

    const float mag_s = mag[s];
    const float srcx = src[s * 3 + 0];
    const float srcy = src[s * 3 + 1];
    const float srcz = src[s * 3 + 2];
    const float sp_mc0 = softplus(mag_coef[0]), sp_mc1 = softplus(mag_coef[1]);
    const float sp_ec0 = softplus(epi_coef[0]), sp_ec1 = softplus(epi_coef[1]);
    const float dc0 = dep_coef[0], dc1 = dep_coef[1];

    for (int i = tid; i < NSTA; i += 256) {
        const int st = s_sta[i];
        float wsum = 0.0f, a0 = 0.0f, a1 = 0.0f;
#pragma unroll
        for (int k = 0; k < KK; ++k) {
            const int g = s_g[k];
            const float* kp = coefs_ker + ((size_t)g * L_N + st) * 3;
            float k0 = softplus(kp[0]);
            float k1 = softplus(kp[1]);
            float k2 = softplus(kp[2]);
            float t0 = s_diff[k][0] / k0;
            float t1 = s_diff[k][1] / k1;
            float t2 = s_diff[k][2] / k2;
            float e  = expf(-0.5f * ((t0 * t0 + t1 * t1) + t2 * t2));
            const float* cp = coefs + ((size_t)g * L_N + st) * 2;
            wsum += e;
            a0 += e * cp[0];
            a1 += e * cp[1];
        }
        if (wsum == 0.0f) wsum = 1.0f;

        const int ph = phase[i];
        float bias = ((ph == 0) ? a0 : a1) / wsum;

        float dx = srcx * 1000.0f - sta[i * 3 + 0] * 1000.0f;
        float dy = srcy * 1000.0f - sta[i * 3 + 1] * 1000.0f;
        float lz = log10f(sqrtf(dx * dx + dy * dy) + 1.0f);
        float ld = log10f(fabsf(srcz - sta[i * 3 + 2]) + 1.0f);

        float mc = (ph == 0) ? sp_mc0 : sp_mc1;
        float ec = (ph == 0) ? sp_ec0 : sp_ec1;
        float dc = (ph == 0) ? dc0 : dc1;

        out[(size_t)s * NSTA + i] = mag_s * mc - ec * lz + dc * ld + bias;
    }
}

extern "C" void kernel_launch(void* const* d_in, const int* in_sizes, int n_in,
                              void* d_out, int out_size, void* d_ws, size_t ws_size,
                              hipStream_t stream) {
    const float* sta       = (const float*)d_in[0];
    const float* src       = (const float*)d_in[1];
    const float* mag       = (const float*)d_in[2];
    const int*   phase     = (const int*)d_in[3];
    const float* x_grid    = (const float*)d_in[4];
    const float* locs_ref  = (const float*)d_in[5];
    const float* mag_coef  = (const float*)d_in[6];
    const float* epi_coef  = (const float*)d_in[7];
    const float* dep_coef  = (const float*)d_in[8];
    const float* coefs     = (const float*)d_in[9];
    const float* coefs_ker = (const float*)d_in[10];
    float* out = (float*)d_out;

    const size_t pk_bytes = (size_t)G_N * NSTA * sizeof(uint2);   // 32 MB
    const size_t tail_ints = (size_t)NSRC * KK + NSTA + G_N + 3 * G_N + 3 * NSRC;
    const size_t need_fast = pk_bytes + tail_ints * 4;

    if (ws_size >= need_fast) {
        uint2* ws_pk   = (uint2*)d_ws;
        int*   ws_idx  = (int*)((char*)d_ws + pk_bytes);
        int*   ws_sta  = ws_idx + (size_t)NSRC * KK;
        int*   ws_used = ws_sta + NSTA;
        float* ws_tg   = (float*)(ws_used + G_N);
        float* ws_ts   = ws_tg + 3 * G_N;

        hipLaunchKernelGGL(sta_prep_kernel, dim3(NSTA), dim3(64), 0, stream,
                           sta, locs_ref, x_grid, src, ws_sta, ws_tg, ws_ts, ws_used);
        hipLaunchKernelGGL(topk_only_kernel, dim3(NSRC), dim3(256), 0, stream,
                           ws_tg, ws_ts, ws_idx, ws_used);
        hipLaunchKernelGGL(pack_kernel, dim3(NBLK), dim3(256), 0, stream,
                           coefs, coefs_ker, ws_sta, phase, ws_used, ws_pk);
        hipLaunchKernelGGL(magnitude_fast_kernel, dim3(NSRC), dim3(256), 0, stream,
                           sta, src, mag, phase, x_grid,
                           mag_coef, epi_coef, dep_coef,
                           ws_pk, ws_idx, out);
    } else {
        int*   ws_sta  = (int*)d_ws;
        int*   ws_idx  = ws_sta + NSTA;
        float* ws_tg   = (float*)(ws_idx + (size_t)NSRC * KK);
        float* ws_ts   = ws_tg + 3 * G_N;

        hipLaunchKernelGGL(sta_prep_kernel, dim3(NSTA), dim3(64), 0, stream,
                           sta, locs_ref, x_grid, src, ws_sta, ws_tg, ws_ts, (int*)nullptr);
        hipLaunchKernelGGL(topk_only_kernel, dim3(NSRC), dim3(256), 0, stream,
                           ws_tg, ws_ts, ws_idx, (int*)nullptr);
        hipLaunchKernelGGL(magnitude_kernel, dim3(NSRC), dim3(256), 0, stream,
                           sta, src, mag, phase, x_grid,
                           mag_coef, epi_coef, dep_coef,
                           coefs, coefs_ker, ws_sta, ws_idx, out);
    }
}

// Round 13
// 114.078 us; speedup vs baseline: 1.1289x; 1.1289x over previous
//
#include <hip/hip_runtime.h>
#include <hip/hip_fp16.h>
#include <cstddef>

#define G_N   10000
#define L_N   1000
#define NSTA  400
#define NSRC  2000
#define KK    15
#define CAP   512

__device__ __forceinline__ float tr1k(float x) {
    // matches reference: _ftrns(x)/1000.0 = (x*1000.0f)/1000.0f, exact f32 div
    return (x * 1000.0f) / 1000.0f;
}

__device__ __forceinline__ float softplus(float x) {
    return fmaxf(x, 0.0f) + log1pf(expf(-fabsf(x)));
}

__device__ __forceinline__ float softplus_fast(float x) {
    return fmaxf(x, 0.0f) + __logf(1.0f + __expf(-fabsf(x)));
}

__device__ __forceinline__ bool lexless(float v1, int i1, float v2, int i2) {
    return (v1 < v2) || (v1 == v2 && i1 < i2);
}

// pack 4 f32 -> 4 fp16 in one 64-bit word
__device__ __forceinline__ unsigned long long pack4h(float a, float b, float c, float d) {
    __half2 lo = __floats2half2_rn(a, b);
    __half2 hi = __floats2half2_rn(c, d);
    unsigned int ulo = *reinterpret_cast<unsigned int*>(&lo);
    unsigned int uhi = *reinterpret_cast<unsigned int*>(&hi);
    return (unsigned long long)ulo | ((unsigned long long)uhi << 32);
}

// ---------------------------------------------------------------------------
// Kernel 1: sta_ind argmin (one wave per station) + tr1k precompute tables
// (tg = tr1k(x_grid), ts = tr1k(src)) + zero used[].
// ---------------------------------------------------------------------------
__global__ void sta_prep_kernel(const float* __restrict__ sta,
                                const float* __restrict__ locs_ref,
                                const float* __restrict__ x_grid,
                                const float* __restrict__ src,
                                int* __restrict__ sta_ind,
                                float* __restrict__ tg,
                                float* __restrict__ ts,
                                int* __restrict__ used) {
#pragma clang fp contract(off)
    const int i    = blockIdx.x;
    const int lane = threadIdx.x;

    const int z = i * 64 + lane;
    for (int p = z; p < 3 * (G_N + NSRC); p += 400 * 64) {
        if (p < 3 * G_N) tg[p] = tr1k(x_grid[p]);
        else             ts[p - 3 * G_N] = tr1k(src[p - 3 * G_N]);
    }
    if (used && z < G_N) used[z] = 0;   // 25600 threads >= G_N

    const float sx = tr1k(sta[i * 3 + 0]);
    const float sy = tr1k(sta[i * 3 + 1]);
    const float sz = tr1k(sta[i * 3 + 2]);
    float best = INFINITY;
    int   bidx = 0x7fffffff;
    for (int j = lane; j < L_N; j += 64) {
        float dx = sx - tr1k(locs_ref[j * 3 + 0]);
        float dy = sy - tr1k(locs_ref[j * 3 + 1]);
        float dz = sz - tr1k(locs_ref[j * 3 + 2]);
        float d  = (dx * dx + dy * dy) + dz * dz;
        if (lexless(d, j, best, bidx)) { best = d; bidx = j; }
    }
    for (int off = 1; off < 64; off <<= 1) {
        float ov = __shfl_xor(best, off);
        int   oi = __shfl_xor(bidx, off);
        if (lexless(ov, oi, best, bidx)) { best = ov; bidx = oi; }
    }
    if (lane == 0) sta_ind[i] = bidx;
}

// ---------------------------------------------------------------------------
// Kernel 2 (v5): exact threshold select; no divisions, no histogram,
// ~5 KB LDS. Unchanged.
// ---------------------------------------------------------------------------
__global__ __launch_bounds__(256, 8) void topk_only_kernel(
    const float* __restrict__ tg, const float* __restrict__ ts,
    int* __restrict__ idx_out, int* __restrict__ used)
{
#pragma clang fp contract(off)
    const int s    = blockIdx.x;
    const int tid  = threadIdx.x;
    const int lane = tid & 63;
    const int wv   = tid >> 6;

    __shared__ float s_min[256];
    __shared__ int   s_cand[CAP];
    __shared__ float s_cd[CAP];
    __shared__ float s_T;
    __shared__ int   s_cnt;
    __shared__ float s_mv[4];
    __shared__ int   s_mi[4];
    __shared__ int   s_ch[KK];

    if (tid == 0) s_cnt = 0;

    const float sx = ts[s * 3 + 0];
    const float sy = ts[s * 3 + 1];
    const float sz = ts[s * 3 + 2];

    // pass 1: per-thread min
    float mymin = INFINITY;
    for (int g = tid; g < G_N; g += 256) {
        float dx = sx - tg[g * 3 + 0];
        float dy = sy - tg[g * 3 + 1];
        float dz = sz - tg[g * 3 + 2];
        float d  = (dx * dx + dy * dy) + dz * dz;
        mymin = fminf(mymin, d);
    }
    s_min[tid] = mymin;
    __syncthreads();

    // wave 0: T = 15th smallest of 256 minima
    if (wv == 0) {
        float m0 = s_min[lane];
        float m1 = s_min[lane + 64];
        float m2 = s_min[lane + 128];
        float m3 = s_min[lane + 192];
        float T = INFINITY;
        for (int r = 0; r < KK; ++r) {
            float lv = m0; int ls = 0;
            if (m1 < lv) { lv = m1; ls = 1; }
            if (m2 < lv) { lv = m2; ls = 2; }
            if (m3 < lv) { lv = m3; ls = 3; }
            float v = lv; int wl = lane;
            for (int off = 1; off < 64; off <<= 1) {
                float ov = __shfl_xor(v, off);
                int   ol = __shfl_xor(wl, off);
                if (ov < v || (ov == v && ol < wl)) { v = ov; wl = ol; }
            }
            T = v;
            if (wl == lane) {
                if (ls == 0) m0 = INFINITY;
                else if (ls == 1) m1 = INFINITY;
                else if (ls == 2) m2 = INFINITY;
                else m3 = INFINITY;
            }
        }
        if (lane == 0) s_T = T;
    }
    __syncthreads();
    const float T = s_T;

    // pass 2: recompute, append survivors
    for (int g = tid; g < G_N; g += 256) {
        float dx = sx - tg[g * 3 + 0];
        float dy = sy - tg[g * 3 + 1];
        float dz = sz - tg[g * 3 + 2];
        float d  = (dx * dx + dy * dy) + dz * dz;
        if (d <= T) {
            int p = atomicAdd(&s_cnt, 1);
            if (p < CAP) { s_cand[p] = g; s_cd[p] = d; }
        }
    }
    __syncthreads();
    const int n = s_cnt;

    if (n <= CAP) {
        if (wv == 0) {
            float vals[KK];
            int   ids[KK];
#pragma unroll
            for (int j = 0; j < KK; ++j) { vals[j] = INFINITY; ids[j] = 0x7fffffff; }
            for (int c = lane; c < n; c += 64) {
                int   g = s_cand[c];
                float d = s_cd[c];
                if (lexless(d, g, vals[KK - 1], ids[KK - 1])) {
                    float cv = d; int ci = g;
#pragma unroll
                    for (int j = 0; j < KK; ++j) {
                        bool sw = lexless(cv, ci, vals[j], ids[j]);
                        float tv = sw ? vals[j] : cv;
                        int   ti = sw ? ids[j]  : ci;
                        vals[j]  = sw ? cv : vals[j];
                        ids[j]   = sw ? ci : ids[j];
                        cv = tv; ci = ti;
                    }
                }
            }
            for (int r = 0; r < KK; ++r) {
                float v  = vals[0];
                int   id = ids[0];
                int   who = lane;
                for (int off = 1; off < 64; off <<= 1) {
                    float ov = __shfl_xor(v, off);
                    int   oi = __shfl_xor(id, off);
                    int   ow = __shfl_xor(who, off);
                    if (lexless(ov, oi, v, id)) { v = ov; id = oi; who = ow; }
                }
                if (lane == 0) {
                    idx_out[s * KK + r] = id;
                    if (used) used[id] = 1;   // benign race; all writers store 1
                }
                if (who == lane) {
#pragma unroll
                    for (int j = 0; j < KK - 1; ++j) { vals[j] = vals[j + 1]; ids[j] = ids[j + 1]; }
                    vals[KK - 1] = INFINITY;
                    ids[KK - 1]  = 0x7fffffff;
                }
            }
        }
    } else {
        // degenerate-ties fallback: exact 15 rounds of block argmin
        for (int r = 0; r < KK; ++r) {
            float v  = INFINITY;
            int   id = 0x7fffffff;
            for (int g = tid; g < G_N; g += 256) {
                bool skip = false;
                for (int j = 0; j < r; ++j) skip = skip || (s_ch[j] == g);
                if (skip) continue;
                float dx = sx - tg[g * 3 + 0];
                float dy = sy - tg[g * 3 + 1];
                float dz = sz - tg[g * 3 + 2];
                float d  = (dx * dx + dy * dy) + dz * dz;
                if (lexless(d, g, v, id)) { v = d; id = g; }
            }
            for (int off = 1; off < 64; off <<= 1) {
                float ov = __shfl_xor(v, off);
                int   oi = __shfl_xor(id, off);
                if (lexless(ov, oi, v, id)) { v = ov; id = oi; }
            }
            if (lane == 0) { s_mv[wv] = v; s_mi[wv] = id; }
            __syncthreads();
            if (tid == 0) {
                float bv = s_mv[0]; int bi = s_mi[0];
                for (int w = 1; w < 4; ++w)
                    if (lexless(s_mv[w], s_mi[w], bv, bi)) { bv = s_mv[w]; bi = s_mi[w]; }
                s_ch[r] = bi;
                idx_out[s * KK + r] = bi;
                if (used) used[bi] = 1;
            }
            __syncthreads();
        }
    }
}

// ---------------------------------------------------------------------------
// Kernel 3: pack (fp16), R9 structure (global_load_lds DMA, single buffer,
// 8 blocks/CU) + NON-TEMPORAL pk stores (64-bit words) so the 32 MB table
// does not evict the 200 MB input stream from L3 between graph replays.
// ---------------------------------------------------------------------------
__global__ __launch_bounds__(256, 8) void pack_kernel(
    const float* __restrict__ coefs, const float* __restrict__ coefs_ker,
    const int* __restrict__ sta_ind, const int* __restrict__ phase,
    const int* __restrict__ used,
    unsigned long long* __restrict__ pk)
{
    const int g = blockIdx.x;
    if (!used[g]) return;            // wave-uniform early exit
    const int tid  = threadIdx.x;
    const int lane = tid & 63;
    const int wv   = tid >> 6;

    // [0,3000) = ker row floats, [3000,5000) = coef row floats, [5000,5120) pad
    __shared__ __align__(16) float s_all[5120];   // 20480 B exactly -> 8 blocks/CU

    const float4* kr4 = (const float4*)(coefs_ker + (size_t)g * (L_N * 3)); // 750 slots
    const float4* cr4 = (const float4*)(coefs     + (size_t)g * (L_N * 2)); // 500 slots

#pragma unroll
    for (int r = 0; r < 5; ++r) {
        const int chunk = wv * 5 + r;          // 0..19, wave-uniform
        const int slot  = chunk * 64 + lane;   // 0..1279, per-lane
        const float4* gp = (slot < 750) ? (kr4 + slot)
                         : (slot < 1250) ? (cr4 + (slot - 750))
                         : (cr4 + 499);        // clamped tail -> LDS pad
        __builtin_amdgcn_global_load_lds(
            (const __attribute__((address_space(1))) void*)gp,
            (__attribute__((address_space(3))) void*)(s_all + (size_t)chunk * 256),
            16, 0, 0);
    }

    // prefetch gather indices (coalesced) while the DMA is in flight
    const int i1  = tid + 256;
    const int st0 = sta_ind[tid];                       // tid < 256 <= NSTA
    const int ph0 = phase[tid];
    const int st1 = (i1 < NSTA) ? sta_ind[i1] : 0;
    const int ph1 = (i1 < NSTA) ? phase[i1] : 0;
    __syncthreads();   // drains vmcnt (global_load_lds) before LDS reads

    const float* s_ker = s_all;          // 3000 floats
    const float* s_c   = s_all + 3000;   // 2000 floats

    {
        float rk0 = 1.0f / softplus_fast(s_ker[st0 * 3 + 0]);
        float rk1 = 1.0f / softplus_fast(s_ker[st0 * 3 + 1]);
        float rk2 = 1.0f / softplus_fast(s_ker[st0 * 3 + 2]);
        float c   = (ph0 == 0) ? s_c[st0 * 2 + 0] : s_c[st0 * 2 + 1];
        __builtin_nontemporal_store(pack4h(rk0, rk1, rk2, c),
                                    &pk[(size_t)g * NSTA + tid]);
    }
    if (i1 < NSTA) {
        float rk0 = 1.0f / softplus_fast(s_ker[st1 * 3 + 0]);
        float rk1 = 1.0f / softplus_fast(s_ker[st1 * 3 + 1]);
        float rk2 = 1.0f / softplus_fast(s_ker[st1 * 3 + 2]);
        float c   = (ph1 == 0) ? s_c[st1 * 2 + 0] : s_c[st1 * 2 + 1];
        __builtin_nontemporal_store(pack4h(rk0, rk1, rk2, c),
                                    &pk[(size_t)g * NSTA + i1]);
    }
}

// ---------------------------------------------------------------------------
// Kernel 4: main fused computation, fast path (fp16 packed table).
// out stores are non-temporal (never re-read) to preserve L3 residency
// of the input rows across graph replays.
// ---------------------------------------------------------------------------
__global__ __launch_bounds__(256, 8) void magnitude_fast_kernel(
    const float* __restrict__ sta, const float* __restrict__ src,
    const float* __restrict__ mag, const int* __restrict__ phase,
    const float* __restrict__ x_grid,
    const float* __restrict__ mag_coef, const float* __restrict__ epi_coef,
    const float* __restrict__ dep_coef,
    const unsigned long long* __restrict__ pk, const int* __restrict__ idx,
    float* __restrict__ out)
{
    const int s   = blockIdx.x;
    const int tid = threadIdx.x;

    __shared__ float s_diff[KK][3];
    __shared__ int   s_g[KK];

    if (tid < KK) {
        int g = idx[s * KK + tid];
        s_g[tid] = g;
        s_diff[tid][0] = tr1k(x_grid[g * 3 + 0]) - tr1k(src[s * 3 + 0]);
        s_diff[tid][1] = tr1k(x_grid[g * 3 + 1]) - tr1k(src[s * 3 + 1]);
        s_diff[tid][2] = tr1k(x_grid[g * 3 + 2]) - tr1k(src[s * 3 + 2]);
    }
    __syncthreads();

    const float mag_s = mag[s];
    const float srcx = src[s * 3 + 0];
    const float srcy = src[s * 3 + 1];
    const float srcz = src[s * 3 + 2];
    const float sp_mc0 = softplus(mag_coef[0]), sp_mc1 = softplus(mag_coef[1]);
    const float sp_ec0 = softplus(epi_coef[0]), sp_ec1 = softplus(epi_coef[1]);
    const float dc0 = dep_coef[0], dc1 = dep_coef[1];

    for (int i = tid; i < NSTA; i += 256) {
        float wsum = 0.0f, a = 0.0f;
#pragma unroll
        for (int k = 0; k < KK; ++k) {
            unsigned long long u = pk[(size_t)s_g[k] * NSTA + i];
            unsigned int ulo = (unsigned int)u;
            unsigned int uhi = (unsigned int)(u >> 32);
            __half2 h01 = *reinterpret_cast<const __half2*>(&ulo);
            __half2 h23 = *reinterpret_cast<const __half2*>(&uhi);
            float2 f01 = __half22float2(h01);
            float2 f23 = __half22float2(h23);
            float t0 = s_diff[k][0] * f01.x;
            float t1 = s_diff[k][1] * f01.y;
            float t2 = s_diff[k][2] * f23.x;
            float e  = __expf(-0.5f * ((t0 * t0 + t1 * t1) + t2 * t2));
            wsum += e;
            a    += e * f23.y;
        }
        if (wsum == 0.0f) wsum = 1.0f;

        const int ph = phase[i];
        float bias = a / wsum;

        float dx = srcx * 1000.0f - sta[i * 3 + 0] * 1000.0f;
        float dy = srcy * 1000.0f - sta[i * 3 + 1] * 1000.0f;
        float lz = __log10f(__fsqrt_rn(dx * dx + dy * dy) + 1.0f);
        float ld = __log10f(fabsf(srcz - sta[i * 3 + 2]) + 1.0f);

        float mc = (ph == 0) ? sp_mc0 : sp_mc1;
        float ec = (ph == 0) ? sp_ec0 : sp_ec1;
        float dc = (ph == 0) ? dc0 : dc1;

        __builtin_nontemporal_store(mag_s * mc - ec * lz + dc * ld + bias,
                                    &out[(size_t)s * NSTA + i]);
    }
}

// ---------------------------------------------------------------------------
// Fallback main kernel (direct gather) if ws can't hold the packed table.
// ---------------------------------------------------------------------------
__global__ __launch_bounds__(256) void magnitude_kernel(
    const float* __restrict__ sta, const float* __restrict__ src,
    const float* __restrict__ mag, const int* __restrict__ phase,
    const float* __restrict__ x_grid,
    const float* __restrict__ mag_coef, const float* __restrict__ epi_coef,
    const float* __restrict__ dep_coef,
    const float* __restrict__ coefs, const float* __restrict__ coefs_ker,
    const int* __restrict__ sta_ind, const int* __restrict__ idx,
    float* __restrict__ out)
{
    const int s   = blockIdx.x;
    const int tid = threadIdx.x;

    __shared__ float s_diff[KK][3];
    __shared__ int   s_g[KK];
    __shared__ int   s_sta[NSTA];

    if (tid < KK) {
        int g = idx[s * KK + tid];
        s_g[tid] = g;
        s_diff[tid][0] = tr1k(x_grid[g * 3 + 0]) - tr1k(src[s * 3 + 0]);
        s_diff[tid][1] = tr1k(x_grid[g * 3 + 1]) - tr1k(src[s * 3 + 1]);
        s_diff[tid][2] = tr1k(x_grid[g * 3 + 2]) - tr1k(src[s * 3 + 2]);
    }
    for (int i = tid; i < NSTA; i += 256) s_sta[i] = sta_ind[i];
    __syncthreads();

    const float mag_s = mag[s];
    const float srcx = src[s * 3 + 0];
    const float srcy = src[s * 3 + 1];
    const float srcz = src[s * 3 + 2];
    const float sp_mc0 = softplus(mag_coef[0]), sp_mc1 = softplus(mag_coef[1]);
    const float sp_ec0 = softplus(epi_coef[0]), sp_ec1 = softplus(epi_coef[1]);
    const float dc0 = dep_coef[0], dc1 = dep_coef[1];

    for (int i = tid; i < NSTA; i += 256) {
        const int st = s_sta[i];
        float wsum = 0.0f, a0 = 0.0f, a1 = 0.0f;
#pragma unroll
        for (int k = 0; k < KK; ++k) {
            const int g = s_g[k];
            const float* kp = coefs_ker + ((size_t)g * L_N + st) * 3;
            float k0 = softplus(kp[0]);
            float k1 = softplus(kp[1]);
            float k2 = softplus(kp[2]);
            float t0 = s_diff[k][0] / k0;
            float t1 = s_diff[k][1] / k1;
            float t2 = s_diff[k][2] / k2;
            float e  = expf(-0.5f * ((t0 * t0 + t1 * t1) + t2 * t2));
            const float* cp = coefs + ((size_t)g * L_N + st) * 2;
            wsum += e;
            a0 += e * cp[0];
            a1 += e * cp[1];
        }
        if (wsum == 0.0f) wsum = 1.0f;

        const int ph = phase[i];
        float bias = ((ph == 0) ? a0 : a1) / wsum;

        float dx = srcx * 1000.0f - sta[i * 3 + 0] * 1000.0f;
        float dy = srcy * 1000.0f - sta[i * 3 + 1] * 1000.0f;
        float lz = log10f(sqrtf(dx * dx + dy * dy) + 1.0f);
        float ld = log10f(fabsf(srcz - sta[i * 3 + 2]) + 1.0f);

        float mc = (ph == 0) ? sp_mc0 : sp_mc1;
        float ec = (ph == 0) ? sp_ec0 : sp_ec1;
        float dc = (ph == 0) ? dc0 : dc1;

        out[(size_t)s * NSTA + i] = mag_s * mc - ec * lz + dc * ld + bias;
    }
}

extern "C" void kernel_launch(void* const* d_in, const int* in_sizes, int n_in,
                              void* d_out, int out_size, void* d_ws, size_t ws_size,
                              hipStream_t stream) {
    const float* sta       = (const float*)d_in[0];
    const float* src       = (const float*)d_in[1];
    const float* mag       = (const float*)d_in[2];
    const int*   phase     = (const int*)d_in[3];
    const float* x_grid    = (const float*)d_in[4];
    const float* locs_ref  = (const float*)d_in[5];
    const float* mag_coef  = (const float*)d_in[6];
    const float* epi_coef  = (const float*)d_in[7];
    const float* dep_coef  = (const float*)d_in[8];
    const float* coefs     = (const float*)d_in[9];
    const float* coefs_ker = (const float*)d_in[10];
    float* out = (float*)d_out;

    const size_t pk_bytes = (size_t)G_N * NSTA * sizeof(unsigned long long);  // 32 MB
    const size_t tail_ints = (size_t)NSRC * KK + NSTA + G_N + 3 * G_N + 3 * NSRC;
    const size_t need_fast = pk_bytes + tail_ints * 4;

    if (ws_size >= need_fast) {
        unsigned long long* ws_pk = (unsigned long long*)d_ws;
        int*   ws_idx  = (int*)((char*)d_ws + pk_bytes);
        int*   ws_sta  = ws_idx + (size_t)NSRC * KK;
        int*   ws_used = ws_sta + NSTA;
        float* ws_tg   = (float*)(ws_used + G_N);
        float* ws_ts   = ws_tg + 3 * G_N;

        hipLaunchKernelGGL(sta_prep_kernel, dim3(NSTA), dim3(64), 0, stream,
                           sta, locs_ref, x_grid, src, ws_sta, ws_tg, ws_ts, ws_used);
        hipLaunchKernelGGL(topk_only_kernel, dim3(NSRC), dim3(256), 0, stream,
                           ws_tg, ws_ts, ws_idx, ws_used);
        hipLaunchKernelGGL(pack_kernel, dim3(G_N), dim3(256), 0, stream,
                           coefs, coefs_ker, ws_sta, phase, ws_used, ws_pk);
        hipLaunchKernelGGL(magnitude_fast_kernel, dim3(NSRC), dim3(256), 0, stream,
                           sta, src, mag, phase, x_grid,
                           mag_coef, epi_coef, dep_coef,
                           ws_pk, ws_idx, out);
    } else {
        int*   ws_sta  = (int*)d_ws;
        int*   ws_idx  = ws_sta + NSTA;
        float* ws_tg   = (float*)(ws_idx + (size_t)NSRC * KK);
        float* ws_ts   = ws_tg + 3 * G_N;

        hipLaunchKernelGGL(sta_prep_kernel, dim3(NSTA), dim3(64), 0, stream,
                           sta, locs_ref, x_grid, src, ws_sta, ws_tg, ws_ts, (int*)nullptr);
        hipLaunchKernelGGL(topk_only_kernel, dim3(NSRC), dim3(256), 0, stream,
                           ws_tg, ws_ts, ws_idx, (int*)nullptr);
        hipLaunchKernelGGL(magnitude_kernel, dim3(NSRC), dim3(256), 0, stream,
                           sta, src, mag, phase, x_grid,
                           mag_coef, epi_coef, dep_coef,
                           coefs, coefs_ker, ws_sta, ws_idx, out);
    }
}